// Round 8
// baseline (233.592 us; speedup 1.0000x reference)
//
#include <hip/hip_runtime.h>
#include <hip/hip_bf16.h>

// DiceActor fused forward, MI355X (gfx950).
// out layout (f32): action[B*32] | pretanh[B*32] | log_prob[B] | pretanh_log_prob[B]
//
// R8 = R3 core (4 waves, wf[16] B-frags in regs, 0-conflict swizzles,
// reg-staged obs->bf16) + 2 tiles/block (grid 2048, wf amortized) +
// issue-early global loads (obs halves & noise issued one MFMA phase ahead)
// + explicit 3-waves/SIMD reg tier (launch_bounds(256,3) -> cap ~170;
// R2/R4/R7 showed hipcc clamps to the tier BELOW the natural live set and
// spills -- ~140 live regs need the 170 tier, not 128).

#define B_TOTAL 262144
#define OBS_D   128
#define LAT     256
#define ACT     32

typedef __attribute__((ext_vector_type(8))) short bf16x8;   // 8 bf16 in 4 VGPRs
typedef __attribute__((ext_vector_type(4))) float f32x4;

__device__ __forceinline__ unsigned short f2bf(float x) {
  __hip_bfloat16 h = __float2bfloat16(x);
  return __builtin_bit_cast(unsigned short, h);
}

__device__ __forceinline__ float ftanh(float x) {
  float ax = fabsf(x);
  float e  = __expf(-2.f * ax);
  float y  = (1.f - e) / (1.f + e);
  return x < 0.f ? -y : y;
}

// ---------------------------------------------------------------------------
// Prep kernel: pack weights as bf16 into d_ws (layout unchanged since R3).
//  region A [0, 65536) bytes: W_bb B-fragments:
//    elem = g*8192 + (t*4+s)*512 + lane*8 + j      (g = 64-col group 0..3)
//    value = bf16( W_bb[k = s*32 + (lane>>4)*8 + j][n = g*64 + t*16 + (lane&15)] )
//  region B [65536, 98304) bytes: head B-fragments:
//    elem = 32768 + ((s*4+u)*64 + lane)*8 + j      (s = k-slice 0..7)
//    value = Wh[n = u*16 + (lane&15)][k = s*32 + (lane>>4)*8 + j]
//    where Wh[n][k]: n<32 -> Wmu[k][n], else Wsg[k][n-32]
// ---------------------------------------------------------------------------
__global__ void dice_prep(const float* __restrict__ Wbb,
                          const float* __restrict__ Wmu,
                          const float* __restrict__ Wsg,
                          unsigned short* __restrict__ wpack) {
  int tid = blockIdx.x * 256 + threadIdx.x;      // 192*256 = 49152 exactly
  if (tid < 32768) {
    int g    = tid >> 13;
    int rem  = tid & 8191;
    int f    = rem >> 9;
    int lane = (rem >> 3) & 63;
    int j    = rem & 7;
    int t = f >> 2, s = f & 3;
    int k = s * 32 + (lane >> 4) * 8 + j;
    int n = g * 64 + t * 16 + (lane & 15);
    wpack[tid] = f2bf(Wbb[k * LAT + n]);
  } else {
    int i    = tid - 32768;                      // [0, 16384)
    int f    = i >> 9;                           // frag 0..31 = s*4+u
    int lane = (i >> 3) & 63;
    int j    = i & 7;
    int s = f >> 2, u = f & 3;
    int n = u * 16 + (lane & 15);
    int k = s * 32 + (lane >> 4) * 8 + j;
    float v = (n < 32) ? Wmu[k * ACT + n] : Wsg[k * ACT + (n - 32)];
    wpack[32768 + i] = f2bf(v);
  }
}

// ---------------------------------------------------------------------------
// Main kernel: 256 threads (4 waves), 128 rows (2x64 tiles) per block,
// grid 2048. LDS: 8K + 8K obs halves + 32K s_h = 48 KB -> 3 blocks/CU.
// ---------------------------------------------------------------------------
__global__ __launch_bounds__(256, 3) void dice_main(
    const float* __restrict__ obs, const float* __restrict__ noise,
    const unsigned short* __restrict__ wpack,
    const float* __restrict__ b_bb, const float* __restrict__ b_mu,
    const float* __restrict__ b_sg, float* __restrict__ out) {

  __shared__ __align__(16) unsigned char s_o0[8192];   // 32 rows x 128 bf16, swizzled
  __shared__ __align__(16) unsigned char s_o1[8192];
  __shared__ __align__(16) unsigned char s_h[32768];   // 64 rows x 256 bf16, swizzled

  const int tid  = threadIdx.x;
  const int wave = tid >> 6, lane = tid & 63;
  const int lrow = lane & 15, lgrp = lane >> 4;
  const int blockRow0 = blockIdx.x * 128;

  // ---- W_bb fragments -> registers (once per 128 rows) ----
  bf16x8 wf[16];
  {
    const bf16x8* wp = (const bf16x8*)wpack + wave * 1024 + lane;
#pragma unroll
    for (int f = 0; f < 16; ++f) wf[f] = wp[f * 64];
  }

  float bbias[4];
#pragma unroll
  for (int t = 0; t < 4; ++t) bbias[t] = b_bb[wave * 64 + t * 16 + lrow];
  const float bmu0 = b_mu[lrow], bmu1 = b_mu[lrow + 16];
  const float bsg0 = b_sg[lrow], bsg1 = b_sg[lrow + 16];

  float* out_act = out;
  float* out_pre = out + (size_t)B_TOTAL * ACT;
  float* out_lp  = out + 2 * (size_t)B_TOTAL * ACT;
  float* out_plp = out_lp + B_TOTAL;
  const bf16x8* hb = (const bf16x8*)(wpack + 32768);

  uint2 hold[4];          // one 32-row half staged in regs (8 VGPRs)
  float n0[4], n1[4];     // prefetched noise (8 VGPRs)

  // ---- helpers ----
  auto ld_half = [&](int tile, int half) {
    const float4* op = (const float4*)obs + (size_t)(blockRow0 + tile * 64 + half * 32) * 32;
#pragma unroll
    for (int i = 0; i < 4; ++i) {
      float4 v = op[i * 256 + tid];
      hold[i].x = (unsigned int)f2bf(v.x) | ((unsigned int)f2bf(v.y) << 16);
      hold[i].y = (unsigned int)f2bf(v.z) | ((unsigned int)f2bf(v.w) << 16);
    }
  };
  auto wr_half = [&](unsigned char* buf) {
#pragma unroll
    for (int i = 0; i < 4; ++i) {
      int flat = i * 256 + tid;
      int m = flat >> 5, kq = flat & 31;
      int byte = m * 256 + ((kq * 8) ^ ((m & 15) << 4));
      *(uint2*)(buf + byte) = hold[i];
    }
  };
  auto ld_noise = [&](int tile) {
#pragma unroll
    for (int r = 0; r < 4; ++r) {
      int row = blockRow0 + tile * 64 + wave * 16 + lgrp * 4 + r;
      n0[r] = noise[(size_t)row * ACT + lrow];
      n1[r] = noise[(size_t)row * ACT + lrow + 16];
    }
  };
  auto backbone = [&](int st, const unsigned char* buf, int mloc) {
    bf16x8 a[4];
#pragma unroll
    for (int s = 0; s < 4; ++s) {
      int abyte = (mloc + lrow) * 256 + ((s * 64 + lgrp * 16) ^ (lrow << 4));
      a[s] = *(const bf16x8*)(buf + abyte);
    }
    f32x4 acc[4];
#pragma unroll
    for (int t = 0; t < 4; ++t) acc[t] = (f32x4)(0.f);
#pragma unroll
    for (int t = 0; t < 4; ++t)
#pragma unroll
      for (int s = 0; s < 4; ++s)
        acc[t] = __builtin_amdgcn_mfma_f32_16x16x32_bf16(a[s], wf[t * 4 + s], acc[t], 0, 0, 0);
#pragma unroll
    for (int t = 0; t < 4; ++t) {
      int col = wave * 64 + t * 16 + lrow;
#pragma unroll
      for (int r = 0; r < 4; ++r) {
        int row = st * 16 + lgrp * 4 + r;
        float v = fmaxf(acc[t][r] + bbias[t], 0.f);
        int byte = row * 512 + ((2 * col) ^ ((row & 15) << 4));
        *(unsigned short*)(s_h + byte) = f2bf(v);
      }
    }
  };
  auto head_epi = [&](int tile) {
    f32x4 acc2[4];
#pragma unroll
    for (int u = 0; u < 4; ++u) acc2[u] = (f32x4)(0.f);
#pragma unroll
    for (int s = 0; s < 8; ++s) {
      int off = (s * 64 + lgrp * 16) ^ (lrow << 4);
      bf16x8 a = *(const bf16x8*)(s_h + (wave * 16 + lrow) * 512 + off);
#pragma unroll
      for (int u = 0; u < 4; ++u) {
        bf16x8 b = hb[(s * 4 + u) * 64 + lane];
        acc2[u] = __builtin_amdgcn_mfma_f32_16x16x32_bf16(a, b, acc2[u], 0, 0, 0);
      }
    }
    float s1v[4], s2v[4];
#pragma unroll
    for (int r = 0; r < 4; ++r) {
      int row = blockRow0 + tile * 64 + wave * 16 + lgrp * 4 + r;
      float mu0 = fminf(fmaxf(acc2[0][r] + bmu0, -7.f), 7.f);
      float mu1 = fminf(fmaxf(acc2[1][r] + bmu1, -7.f), 7.f);
      float ls0 = fminf(fmaxf(acc2[2][r] + bsg0, -2.f), 5.f);
      float ls1 = fminf(fmaxf(acc2[3][r] + bsg1, -2.f), 5.f);
      float sp0 = __expf(0.5f * ls0), sp1 = __expf(0.5f * ls1);
      float p0 = fmaf(sp0, n0[r], mu0), p1 = fmaf(sp1, n1[r], mu1);
      float a0 = ftanh(p0), a1 = ftanh(p1);
      // (pretanh-mu)^2/std == noise^2 analytically
      float t1 = fmaf(n0[r], n0[r], ls0) + fmaf(n1[r], n1[r], ls1);
      float t2 = __logf(1.f - a0 * a0 + 1e-6f) + __logf(1.f - a1 * a1 + 1e-6f);
      out_act[(size_t)row * ACT + lrow]      = a0;
      out_act[(size_t)row * ACT + lrow + 16] = a1;
      out_pre[(size_t)row * ACT + lrow]      = p0;
      out_pre[(size_t)row * ACT + lrow + 16] = p1;
      s1v[r] = t1;
      s2v[r] = t2;
    }
#pragma unroll
    for (int m = 1; m < 16; m <<= 1) {
#pragma unroll
      for (int r = 0; r < 4; ++r) {
        s1v[r] += __shfl_xor(s1v[r], m, 64);
        s2v[r] += __shfl_xor(s2v[r], m, 64);
      }
    }
    if (lrow < 4) {
      int r = lrow;
      float s1 = (r == 0) ? s1v[0] : (r == 1) ? s1v[1] : (r == 2) ? s1v[2] : s1v[3];
      float s2 = (r == 0) ? s2v[0] : (r == 1) ? s2v[1] : (r == 2) ? s2v[2] : s2v[3];
      int row = blockRow0 + tile * 64 + wave * 16 + lgrp * 4 + r;
      float plp = -0.5f * s1 - 29.406033062549525f;   // 0.5*32*log(2*pi)
      out_plp[row] = plp;
      out_lp[row]  = plp - s2;
    }
  };

  // ================= tile 0 =================
  ld_half(0, 0); wr_half(s_o0);
  __syncthreads();                                   // S1: s_o0 ready

  ld_half(0, 1); ld_noise(0);                        // issue early
  backbone(0, s_o0, 0); backbone(1, s_o0, 16);
  wr_half(s_o1);
  __syncthreads();                                   // S2: s_o1 ready

  ld_half(1, 0);                                     // prefetch tile1 half0
  backbone(2, s_o1, 0); backbone(3, s_o1, 16);
  wr_half(s_o0);                                     // tile1 half0 -> s_o0 (free since S2)
  __syncthreads();                                   // S3: s_h + tile1 s_o0 ready

  head_epi(0);
  __syncthreads();                                   // S4: s_h reads done

  // ================= tile 1 =================
  ld_half(1, 1); ld_noise(1);                        // issue early
  backbone(0, s_o0, 0); backbone(1, s_o0, 16);
  wr_half(s_o1);
  __syncthreads();                                   // S5: s_o1 ready

  backbone(2, s_o1, 0); backbone(3, s_o1, 16);
  __syncthreads();                                   // S6: s_h ready

  head_epi(1);
}

extern "C" void kernel_launch(void* const* d_in, const int* in_sizes, int n_in,
                              void* d_out, int out_size, void* d_ws, size_t ws_size,
                              hipStream_t stream) {
  const float* obs = (const float*)d_in[0];
  const float* noi = (const float*)d_in[1];
  const float* Wbb = (const float*)d_in[2];
  const float* bbb = (const float*)d_in[3];
  const float* Wmu = (const float*)d_in[4];
  const float* bmu = (const float*)d_in[5];
  const float* Wsg = (const float*)d_in[6];
  const float* bsg = (const float*)d_in[7];
  unsigned short* wpack = (unsigned short*)d_ws;   // needs 98304 bytes

  hipLaunchKernelGGL(dice_prep, dim3(192), dim3(256), 0, stream, Wbb, Wmu, Wsg, wpack);
  hipLaunchKernelGGL(dice_main, dim3(B_TOTAL / 128), dim3(256), 0, stream,
                     obs, noi, wpack, bbb, bmu, bsg, (float*)d_out);
}

// Round 9
// 94.140 us; speedup vs baseline: 2.4813x; 2.4813x over previous
//
#include <hip/hip_runtime.h>
#include <hip/hip_bf16.h>

// DiceActor fused forward, MI355X (gfx950).
// out layout (f32): action[B*32] | pretanh[B*32] | log_prob[B] | pretanh_log_prob[B]
//
// R9 = R3 core with ALL global latency collapsed into one overlapped drain:
//  - obs staged f32 via __builtin_amdgcn_global_load_lds (width 16): no VGPR
//    round-trip, no staging VALU; bank-swizzle achieved by pre-swizzling the
//    per-lane global SOURCE address (involution inner^=(row&7)<<4), read side
//    applies the same XOR (m173 pattern).
//  - obs DMA + noise + biases issued up front; ONE __syncthreads drains all
//    (its vmcnt(0) covers the DMA). 2 barriers total (R3 had 4).
//  - f32->bf16 conversion moved to fragment read (VALU had headroom).
//  - launch_bounds(256,2) kept; live set stays R3-small. hipcc will not
//    allocate >128 VGPR here (R7/R8 evidence) -- do not approach it.

#define B_TOTAL 262144
#define OBS_D   128
#define LAT     256
#define ACT     32

typedef __attribute__((ext_vector_type(8))) short bf16x8;   // 8 bf16 in 4 VGPRs
typedef __attribute__((ext_vector_type(4))) float f32x4;

__device__ __forceinline__ unsigned short f2bf(float x) {
  __hip_bfloat16 h = __float2bfloat16(x);
  return __builtin_bit_cast(unsigned short, h);
}

__device__ __forceinline__ float ftanh(float x) {
  float ax = fabsf(x);
  float e  = __expf(-2.f * ax);
  float y  = (1.f - e) / (1.f + e);
  return x < 0.f ? -y : y;
}

// ---------------------------------------------------------------------------
// Prep kernel: pack weights as bf16 into d_ws (layout unchanged since R3).
//  region A [0, 65536) bytes: W_bb B-fragments:
//    elem = g*8192 + (t*4+s)*512 + lane*8 + j      (g = 64-col group 0..3)
//    value = bf16( W_bb[k = s*32 + (lane>>4)*8 + j][n = g*64 + t*16 + (lane&15)] )
//  region B [65536, 98304) bytes: head B-fragments:
//    elem = 32768 + ((s*4+u)*64 + lane)*8 + j      (s = k-slice 0..7)
//    value = Wh[n = u*16 + (lane&15)][k = s*32 + (lane>>4)*8 + j]
//    where Wh[n][k]: n<32 -> Wmu[k][n], else Wsg[k][n-32]
// ---------------------------------------------------------------------------
__global__ void dice_prep(const float* __restrict__ Wbb,
                          const float* __restrict__ Wmu,
                          const float* __restrict__ Wsg,
                          unsigned short* __restrict__ wpack) {
  int tid = blockIdx.x * 256 + threadIdx.x;      // 192*256 = 49152 exactly
  if (tid < 32768) {
    int g    = tid >> 13;
    int rem  = tid & 8191;
    int f    = rem >> 9;
    int lane = (rem >> 3) & 63;
    int j    = rem & 7;
    int t = f >> 2, s = f & 3;
    int k = s * 32 + (lane >> 4) * 8 + j;
    int n = g * 64 + t * 16 + (lane & 15);
    wpack[tid] = f2bf(Wbb[k * LAT + n]);
  } else {
    int i    = tid - 32768;                      // [0, 16384)
    int f    = i >> 9;                           // frag 0..31 = s*4+u
    int lane = (i >> 3) & 63;
    int j    = i & 7;
    int s = f >> 2, u = f & 3;
    int n = u * 16 + (lane & 15);
    int k = s * 32 + (lane >> 4) * 8 + j;
    float v = (n < 32) ? Wmu[k * ACT + n] : Wsg[k * ACT + (n - 32)];
    wpack[32768 + i] = f2bf(v);
  }
}

// ---------------------------------------------------------------------------
// Main kernel: 256 threads (4 waves), 64 rows per block, grid 4096.
// LDS: s_of 32K (64 rows x 128 f32, XOR-swizzled) + s_h 32K = 64 KB.
// ---------------------------------------------------------------------------
__global__ __launch_bounds__(256, 2) void dice_main(
    const float* __restrict__ obs, const float* __restrict__ noise,
    const unsigned short* __restrict__ wpack,
    const float* __restrict__ b_bb, const float* __restrict__ b_mu,
    const float* __restrict__ b_sg, float* __restrict__ out) {

  __shared__ __align__(16) unsigned char s_of[32768];  // obs f32, swizzled
  __shared__ __align__(16) unsigned char s_h[32768];   // 64 rows x 256 bf16, swizzled

  const int tid  = threadIdx.x;
  const int wave = tid >> 6, lane = tid & 63;
  const int lrow = lane & 15, lgrp = lane >> 4;
  const int blockRow0 = blockIdx.x * 64;

  // ---- 1) issue obs DMA: wave w stages rows [w*16, w*16+16), 8 x 1KB ----
  //  LDS byte p = w*8192 + it*1024 + lane*16 ; row = p>>9, inner = p&511.
  //  Source global byte = row*512 + (inner ^ ((row&7)<<4))  [involution]
  {
    const char* gb = (const char*)(obs + (size_t)blockRow0 * OBS_D);
    const int rsub  = lane >> 5;              // 0..1
    const int inner = (lane & 31) * 16;       // 0..496
#pragma unroll
    for (int it = 0; it < 8; ++it) {
      int row_l = wave * 16 + it * 2 + rsub;
      int src   = inner ^ ((row_l & 7) << 4);
      const void* g = gb + (size_t)row_l * 512 + src;
      void* l = s_of + wave * 8192 + it * 1024;    // wave-uniform base
      __builtin_amdgcn_global_load_lds(
          (const __attribute__((address_space(1))) unsigned int*)g,
          (__attribute__((address_space(3))) unsigned int*)l, 16, 0, 0);
    }
  }

  // ---- 2) noise + bias prefetch (in flight until use) ----
  float n0[4], n1[4];
#pragma unroll
  for (int r = 0; r < 4; ++r) {
    int row = blockRow0 + wave * 16 + lgrp * 4 + r;
    n0[r] = noise[(size_t)row * ACT + lrow];
    n1[r] = noise[(size_t)row * ACT + lrow + 16];
  }
  float bbias[4];
#pragma unroll
  for (int t = 0; t < 4; ++t) bbias[t] = b_bb[wave * 64 + t * 16 + lrow];
  const float bmu0 = b_mu[lrow], bmu1 = b_mu[lrow + 16];
  const float bsg0 = b_sg[lrow], bsg1 = b_sg[lrow + 16];

  __syncthreads();   // drains vmcnt(0): obs DMA complete (noise/bias too)

  // ---- 3) backbone: 4 strips of 16 rows, cvt f32->bf16 at fragment read ----
  const bf16x8* wp = (const bf16x8*)wpack + wave * 1024 + lane;
#pragma unroll
  for (int st = 0; st < 4; ++st) {
    const int rg = st * 16 + lrow;
    const int sw = (rg & 7) << 4;
    const unsigned char* rb = s_of + rg * 512;
    bf16x8 a[4];
#pragma unroll
    for (int s = 0; s < 4; ++s) {
      int c0 = s * 128 + lgrp * 32;
      f32x4 lo = *(const f32x4*)(rb + ((c0     ) ^ sw));
      f32x4 hi = *(const f32x4*)(rb + ((c0 + 16) ^ sw));
      bf16x8 t;
      t[0] = (short)f2bf(lo[0]); t[1] = (short)f2bf(lo[1]);
      t[2] = (short)f2bf(lo[2]); t[3] = (short)f2bf(lo[3]);
      t[4] = (short)f2bf(hi[0]); t[5] = (short)f2bf(hi[1]);
      t[6] = (short)f2bf(hi[2]); t[7] = (short)f2bf(hi[3]);
      a[s] = t;
    }
    f32x4 acc[4];
#pragma unroll
    for (int t = 0; t < 4; ++t) acc[t] = (f32x4)(0.f);
#pragma unroll
    for (int t = 0; t < 4; ++t)
#pragma unroll
      for (int s = 0; s < 4; ++s)
        acc[t] = __builtin_amdgcn_mfma_f32_16x16x32_bf16(a[s], wp[(t * 4 + s) * 64], acc[t], 0, 0, 0);
#pragma unroll
    for (int t = 0; t < 4; ++t) {
      int col = wave * 64 + t * 16 + lrow;
#pragma unroll
      for (int r = 0; r < 4; ++r) {
        int row = st * 16 + lgrp * 4 + r;
        float v = fmaxf(acc[t][r] + bbias[t], 0.f);
        int byte = row * 512 + ((2 * col) ^ ((row & 15) << 4));
        *(unsigned short*)(s_h + byte) = f2bf(v);
      }
    }
  }

  __syncthreads();   // s_h complete across waves

  // ---- 4) head GEMM: rows [wave*16, wave*16+16) ----
  const bf16x8* hb = (const bf16x8*)(wpack + 32768);
  f32x4 acc2[4];
#pragma unroll
  for (int u = 0; u < 4; ++u) acc2[u] = (f32x4)(0.f);
#pragma unroll
  for (int s = 0; s < 8; ++s) {
    int off = (s * 64 + lgrp * 16) ^ (lrow << 4);
    bf16x8 a = *(const bf16x8*)(s_h + (wave * 16 + lrow) * 512 + off);
#pragma unroll
    for (int u = 0; u < 4; ++u) {
      bf16x8 b = hb[(s * 4 + u) * 64 + lane];
      acc2[u] = __builtin_amdgcn_mfma_f32_16x16x32_bf16(a, b, acc2[u], 0, 0, 0);
    }
  }

  // ---- 5) epilogue (noise already in registers) ----
  float* out_act = out;
  float* out_pre = out + (size_t)B_TOTAL * ACT;
  float* out_lp  = out + 2 * (size_t)B_TOTAL * ACT;
  float* out_plp = out_lp + B_TOTAL;

  float s1v[4], s2v[4];
#pragma unroll
  for (int r = 0; r < 4; ++r) {
    int row = blockRow0 + wave * 16 + lgrp * 4 + r;
    float mu0 = fminf(fmaxf(acc2[0][r] + bmu0, -7.f), 7.f);
    float mu1 = fminf(fmaxf(acc2[1][r] + bmu1, -7.f), 7.f);
    float ls0 = fminf(fmaxf(acc2[2][r] + bsg0, -2.f), 5.f);
    float ls1 = fminf(fmaxf(acc2[3][r] + bsg1, -2.f), 5.f);
    float sp0 = __expf(0.5f * ls0), sp1 = __expf(0.5f * ls1);
    float p0 = fmaf(sp0, n0[r], mu0), p1 = fmaf(sp1, n1[r], mu1);
    float a0 = ftanh(p0), a1 = ftanh(p1);
    // (pretanh-mu)^2/std == noise^2 analytically
    float t1 = fmaf(n0[r], n0[r], ls0) + fmaf(n1[r], n1[r], ls1);
    float t2 = __logf(1.f - a0 * a0 + 1e-6f) + __logf(1.f - a1 * a1 + 1e-6f);
    out_act[(size_t)row * ACT + lrow]      = a0;
    out_act[(size_t)row * ACT + lrow + 16] = a1;
    out_pre[(size_t)row * ACT + lrow]      = p0;
    out_pre[(size_t)row * ACT + lrow + 16] = p1;
    s1v[r] = t1;
    s2v[r] = t2;
  }
#pragma unroll
  for (int m = 1; m < 16; m <<= 1) {
#pragma unroll
    for (int r = 0; r < 4; ++r) {
      s1v[r] += __shfl_xor(s1v[r], m, 64);
      s2v[r] += __shfl_xor(s2v[r], m, 64);
    }
  }
  if (lrow < 4) {
    int r = lrow;
    float s1 = (r == 0) ? s1v[0] : (r == 1) ? s1v[1] : (r == 2) ? s1v[2] : s1v[3];
    float s2 = (r == 0) ? s2v[0] : (r == 1) ? s2v[1] : (r == 2) ? s2v[2] : s2v[3];
    int row = blockRow0 + wave * 16 + lgrp * 4 + r;
    float plp = -0.5f * s1 - 29.406033062549525f;   // 0.5*32*log(2*pi)
    out_plp[row] = plp;
    out_lp[row]  = plp - s2;
  }
}

extern "C" void kernel_launch(void* const* d_in, const int* in_sizes, int n_in,
                              void* d_out, int out_size, void* d_ws, size_t ws_size,
                              hipStream_t stream) {
  const float* obs = (const float*)d_in[0];
  const float* noi = (const float*)d_in[1];
  const float* Wbb = (const float*)d_in[2];
  const float* bbb = (const float*)d_in[3];
  const float* Wmu = (const float*)d_in[4];
  const float* bmu = (const float*)d_in[5];
  const float* Wsg = (const float*)d_in[6];
  const float* bsg = (const float*)d_in[7];
  unsigned short* wpack = (unsigned short*)d_ws;   // needs 98304 bytes

  hipLaunchKernelGGL(dice_prep, dim3(192), dim3(256), 0, stream, Wbb, Wmu, Wsg, wpack);
  hipLaunchKernelGGL(dice_main, dim3(B_TOTAL / 64), dim3(256), 0, stream,
                     obs, noi, wpack, bbb, bmu, bsg, (float*)d_out);
}

// Round 10
// 83.816 us; speedup vs baseline: 2.7869x; 1.1232x over previous
//
#include <hip/hip_runtime.h>
#include <hip/hip_bf16.h>

// DiceActor fused forward, MI355X (gfx950).
// out layout (f32): action[B*32] | pretanh[B*32] | log_prob[B] | pretanh_log_prob[B]
//
// R10 = R3's exact proven phases (same swizzles, bf16 reg-staging, small live
// set) x 2 tiles per block (128 rows, grid 2048 -> halves per-row weight
// streaming) + issue-early loads (obs halves & noise issued one full phase
// before use; raw f32 kept in named g0..g3, cvt at LDS-write, off the read
// path). NO lambdas / captured arrays (R7/R8's 400MB-scratch trap). 6 syncs
// per 128 rows vs R3's 8. LDS 8+8+32 = 48KB -> 3 blocks/CU. launch_bounds
// (256,2) -- natural ~100-reg live set, no forced tier (R2/R4/R7/R8 lesson).

#define B_TOTAL 262144
#define OBS_D   128
#define LAT     256
#define ACT     32

typedef __attribute__((ext_vector_type(8))) short bf16x8;   // 8 bf16 in 4 VGPRs
typedef __attribute__((ext_vector_type(4))) float f32x4;

__device__ __forceinline__ unsigned short f2bf(float x) {
  __hip_bfloat16 h = __float2bfloat16(x);
  return __builtin_bit_cast(unsigned short, h);
}

__device__ __forceinline__ float ftanh(float x) {
  float ax = fabsf(x);
  float e  = __expf(-2.f * ax);
  float y  = (1.f - e) / (1.f + e);
  return x < 0.f ? -y : y;
}

// ---------------------------------------------------------------------------
// Prep kernel: pack weights as bf16 into d_ws (layout unchanged since R3).
//  region A [0, 65536) bytes: W_bb B-fragments:
//    elem = g*8192 + (t*4+s)*512 + lane*8 + j      (g = 64-col group 0..3)
//    value = bf16( W_bb[k = s*32 + (lane>>4)*8 + j][n = g*64 + t*16 + (lane&15)] )
//  region B [65536, 98304) bytes: head B-fragments:
//    elem = 32768 + ((s*4+u)*64 + lane)*8 + j      (s = k-slice 0..7)
//    value = Wh[n = u*16 + (lane&15)][k = s*32 + (lane>>4)*8 + j]
//    where Wh[n][k]: n<32 -> Wmu[k][n], else Wsg[k][n-32]
// ---------------------------------------------------------------------------
__global__ void dice_prep(const float* __restrict__ Wbb,
                          const float* __restrict__ Wmu,
                          const float* __restrict__ Wsg,
                          unsigned short* __restrict__ wpack) {
  int tid = blockIdx.x * 256 + threadIdx.x;      // 192*256 = 49152 exactly
  if (tid < 32768) {
    int g    = tid >> 13;
    int rem  = tid & 8191;
    int f    = rem >> 9;
    int lane = (rem >> 3) & 63;
    int j    = rem & 7;
    int t = f >> 2, s = f & 3;
    int k = s * 32 + (lane >> 4) * 8 + j;
    int n = g * 64 + t * 16 + (lane & 15);
    wpack[tid] = f2bf(Wbb[k * LAT + n]);
  } else {
    int i    = tid - 32768;                      // [0, 16384)
    int f    = i >> 9;                           // frag 0..31 = s*4+u
    int lane = (i >> 3) & 63;
    int j    = i & 7;
    int s = f >> 2, u = f & 3;
    int n = u * 16 + (lane & 15);
    int k = s * 32 + (lane >> 4) * 8 + j;
    float v = (n < 32) ? Wmu[k * ACT + n] : Wsg[k * ACT + (n - 32)];
    wpack[32768 + i] = f2bf(v);
  }
}

// ---------------------------------------------------------------------------
// Main kernel: 256 threads (4 waves), 128 rows (2x64-row tiles) per block,
// grid 2048. LDS: s_o0/s_o1 8KB (32 rows x 128 bf16, swizzled) + s_h 32KB.
// ---------------------------------------------------------------------------
__global__ __launch_bounds__(256, 2) void dice_main(
    const float* __restrict__ obs, const float* __restrict__ noise,
    const unsigned short* __restrict__ wpack,
    const float* __restrict__ b_bb, const float* __restrict__ b_mu,
    const float* __restrict__ b_sg, float* __restrict__ out) {

  __shared__ __align__(16) unsigned char s_o0[8192];
  __shared__ __align__(16) unsigned char s_o1[8192];
  __shared__ __align__(16) unsigned char s_h[32768];

  const int tid  = threadIdx.x;
  const int wave = tid >> 6, lane = tid & 63;
  const int lrow = lane & 15, lgrp = lane >> 4;
  const int blockRow0 = blockIdx.x * 128;

  float bbias[4];
#pragma unroll
  for (int t = 0; t < 4; ++t) bbias[t] = b_bb[wave * 64 + t * 16 + lrow];
  const float bmu0 = b_mu[lrow], bmu1 = b_mu[lrow + 16];
  const float bsg0 = b_sg[lrow], bsg1 = b_sg[lrow + 16];

  float* out_act = out;
  float* out_pre = out + (size_t)B_TOTAL * ACT;
  float* out_lp  = out + 2 * (size_t)B_TOTAL * ACT;
  float* out_plp = out_lp + B_TOTAL;

  const bf16x8* wp = (const bf16x8*)wpack + wave * 1024 + lane;
  const bf16x8* hb = (const bf16x8*)(wpack + 32768);

  float4 g0, g1, g2, g3;     // staged obs half (raw f32, 16 VGPRs)
  float n0[4], n1[4];        // prefetched noise

// ---- issue one 32-row obs half: tile t, half hf -> g0..g3 ----
#define LD_HALF(t, hf) {                                                      \
    const float4* op = (const float4*)obs +                                   \
        (size_t)(blockRow0 + (t) * 64 + (hf) * 32) * 32;                      \
    g0 = op[tid]; g1 = op[256 + tid]; g2 = op[512 + tid]; g3 = op[768 + tid]; \
  }

// ---- cvt + swizzled write of g0..g3 into an 8KB obs buffer ----
#define PW(buf, i, g) {                                                       \
    int flat = (i) * 256 + tid;                                               \
    int m = flat >> 5, kq = flat & 31;                                        \
    int byte = m * 256 + ((kq * 8) ^ ((m & 15) << 4));                        \
    unsigned int lo = (unsigned int)f2bf((g).x) | ((unsigned int)f2bf((g).y) << 16); \
    unsigned int hi = (unsigned int)f2bf((g).z) | ((unsigned int)f2bf((g).w) << 16); \
    *(uint2*)((buf) + byte) = make_uint2(lo, hi);                             \
  }
#define WR_HALF(buf) { PW(buf, 0, g0) PW(buf, 1, g1) PW(buf, 2, g2) PW(buf, 3, g3) }

#define LD_NOISE(t) {                                                         \
    _Pragma("unroll")                                                         \
    for (int r = 0; r < 4; ++r) {                                             \
      int row = blockRow0 + (t) * 64 + wave * 16 + lgrp * 4 + r;              \
      n0[r] = noise[(size_t)row * ACT + lrow];                                \
      n1[r] = noise[(size_t)row * ACT + lrow + 16];                           \
    }                                                                         \
  }

// ---- one 16-row backbone strip from obs buffer `buf` (local rows mloc..mloc+15) ----
#define BB_STRIP(st, buf, mloc) {                                             \
    bf16x8 a_[4];                                                             \
    _Pragma("unroll")                                                         \
    for (int s = 0; s < 4; ++s) {                                             \
      int abyte = ((mloc) + lrow) * 256 + ((s * 64 + lgrp * 16) ^ (lrow << 4)); \
      a_[s] = *(const bf16x8*)((buf) + abyte);                                \
    }                                                                         \
    f32x4 acc_[4];                                                            \
    _Pragma("unroll")                                                         \
    for (int t = 0; t < 4; ++t) acc_[t] = (f32x4)(0.f);                       \
    _Pragma("unroll")                                                         \
    for (int t = 0; t < 4; ++t)                                               \
      _Pragma("unroll")                                                       \
      for (int s = 0; s < 4; ++s)                                             \
        acc_[t] = __builtin_amdgcn_mfma_f32_16x16x32_bf16(a_[s], wp[(t * 4 + s) * 64], acc_[t], 0, 0, 0); \
    _Pragma("unroll")                                                         \
    for (int t = 0; t < 4; ++t) {                                             \
      int col = wave * 64 + t * 16 + lrow;                                    \
      _Pragma("unroll")                                                       \
      for (int r = 0; r < 4; ++r) {                                           \
        int row = (st) * 16 + lgrp * 4 + r;                                   \
        float v = fmaxf(acc_[t][r] + bbias[t], 0.f);                          \
        int byte = row * 512 + ((2 * col) ^ ((row & 15) << 4));               \
        *(unsigned short*)(s_h + byte) = f2bf(v);                             \
      }                                                                       \
    }                                                                         \
  }

// ---- head GEMM + epilogue for tile t (uses prefetched n0/n1) ----
#define HEAD_EPI(tt) {                                                        \
    f32x4 acc2[4];                                                            \
    _Pragma("unroll")                                                         \
    for (int u = 0; u < 4; ++u) acc2[u] = (f32x4)(0.f);                       \
    _Pragma("unroll")                                                         \
    for (int s = 0; s < 8; ++s) {                                             \
      int off = (s * 64 + lgrp * 16) ^ (lrow << 4);                           \
      bf16x8 a_ = *(const bf16x8*)(s_h + (wave * 16 + lrow) * 512 + off);     \
      _Pragma("unroll")                                                       \
      for (int u = 0; u < 4; ++u) {                                           \
        bf16x8 b_ = hb[(s * 4 + u) * 64 + lane];                              \
        acc2[u] = __builtin_amdgcn_mfma_f32_16x16x32_bf16(a_, b_, acc2[u], 0, 0, 0); \
      }                                                                       \
    }                                                                         \
    float s1v[4], s2v[4];                                                     \
    _Pragma("unroll")                                                         \
    for (int r = 0; r < 4; ++r) {                                             \
      int row = blockRow0 + (tt) * 64 + wave * 16 + lgrp * 4 + r;             \
      float mu0 = fminf(fmaxf(acc2[0][r] + bmu0, -7.f), 7.f);                 \
      float mu1 = fminf(fmaxf(acc2[1][r] + bmu1, -7.f), 7.f);                 \
      float ls0 = fminf(fmaxf(acc2[2][r] + bsg0, -2.f), 5.f);                 \
      float ls1 = fminf(fmaxf(acc2[3][r] + bsg1, -2.f), 5.f);                 \
      float sp0 = __expf(0.5f * ls0), sp1 = __expf(0.5f * ls1);               \
      float p0 = fmaf(sp0, n0[r], mu0), p1 = fmaf(sp1, n1[r], mu1);           \
      float a0 = ftanh(p0), a1 = ftanh(p1);                                   \
      float t1 = fmaf(n0[r], n0[r], ls0) + fmaf(n1[r], n1[r], ls1);           \
      float t2 = __logf(1.f - a0 * a0 + 1e-6f) + __logf(1.f - a1 * a1 + 1e-6f); \
      out_act[(size_t)row * ACT + lrow]      = a0;                            \
      out_act[(size_t)row * ACT + lrow + 16] = a1;                            \
      out_pre[(size_t)row * ACT + lrow]      = p0;                            \
      out_pre[(size_t)row * ACT + lrow + 16] = p1;                            \
      s1v[r] = t1;                                                            \
      s2v[r] = t2;                                                            \
    }                                                                         \
    _Pragma("unroll")                                                         \
    for (int m = 1; m < 16; m <<= 1) {                                        \
      _Pragma("unroll")                                                       \
      for (int r = 0; r < 4; ++r) {                                           \
        s1v[r] += __shfl_xor(s1v[r], m, 64);                                  \
        s2v[r] += __shfl_xor(s2v[r], m, 64);                                  \
      }                                                                       \
    }                                                                         \
    if (lrow < 4) {                                                           \
      int r = lrow;                                                           \
      float s1 = (r == 0) ? s1v[0] : (r == 1) ? s1v[1] : (r == 2) ? s1v[2] : s1v[3]; \
      float s2 = (r == 0) ? s2v[0] : (r == 1) ? s2v[1] : (r == 2) ? s2v[2] : s2v[3]; \
      int row = blockRow0 + (tt) * 64 + wave * 16 + lgrp * 4 + r;             \
      float plp = -0.5f * s1 - 29.406033062549525f;                           \
      out_plp[row] = plp;                                                     \
      out_lp[row]  = plp - s2;                                                \
    }                                                                         \
  }

  // ================= schedule =================
  LD_NOISE(0);
  LD_HALF(0, 0);
  WR_HALF(s_o0);
  __syncthreads();                       // S1: s_o0 ready

  LD_HALF(0, 1);                         // in flight under bb01
  BB_STRIP(0, s_o0, 0);  BB_STRIP(1, s_o0, 16);
  WR_HALF(s_o1);
  __syncthreads();                       // S2: s_o1 ready

  LD_HALF(1, 0);                         // tile1 half0 in flight under bb23
  BB_STRIP(2, s_o1, 0);  BB_STRIP(3, s_o1, 16);
  WR_HALF(s_o0);                         // tile1 half0 -> s_o0 (free since S2)
  __syncthreads();                       // S3: s_h + tile1 s_o0 ready

  LD_HALF(1, 1);                         // in flight under head+epilogue
  HEAD_EPI(0);
  __syncthreads();                       // S4: s_h reads done; s_o1 free

  LD_NOISE(1);
  WR_HALF(s_o1);                         // tile1 half1
  BB_STRIP(0, s_o0, 0);  BB_STRIP(1, s_o0, 16);
  __syncthreads();                       // S5: s_o1 ready

  BB_STRIP(2, s_o1, 0);  BB_STRIP(3, s_o1, 16);
  __syncthreads();                       // S6: s_h ready

  HEAD_EPI(1);

#undef LD_HALF
#undef PW
#undef WR_HALF
#undef LD_NOISE
#undef BB_STRIP
#undef HEAD_EPI
}

extern "C" void kernel_launch(void* const* d_in, const int* in_sizes, int n_in,
                              void* d_out, int out_size, void* d_ws, size_t ws_size,
                              hipStream_t stream) {
  const float* obs = (const float*)d_in[0];
  const float* noi = (const float*)d_in[1];
  const float* Wbb = (const float*)d_in[2];
  const float* bbb = (const float*)d_in[3];
  const float* Wmu = (const float*)d_in[4];
  const float* bmu = (const float*)d_in[5];
  const float* Wsg = (const float*)d_in[6];
  const float* bsg = (const float*)d_in[7];
  unsigned short* wpack = (unsigned short*)d_ws;   // needs 98304 bytes

  hipLaunchKernelGGL(dice_prep, dim3(192), dim3(256), 0, stream, Wbb, Wmu, Wsg, wpack);
  hipLaunchKernelGGL(dice_main, dim3(B_TOTAL / 128), dim3(256), 0, stream,
                     obs, noi, wpack, bbb, bmu, bsg, (float*)d_out);
}